// Round 6
// baseline (333.228 us; speedup 1.0000x reference)
//
#include <hip/hip_runtime.h>
#include <hip/hip_bf16.h>
#include <math.h>

#define BATCH 4096
#define IDIM 78
#define DM 256
#define DI 1024
#define NL 4

typedef __attribute__((ext_vector_type(8))) short bf16x8;
typedef __attribute__((ext_vector_type(4))) float f32x4;

__device__ __forceinline__ float siluf(float v){ return v / (1.0f + __expf(-v)); }
__device__ __forceinline__ float softplusf(float v){ return (v > 20.0f) ? v : log1pf(__expf(v)); }
__device__ __forceinline__ ushort f2bf(float f){
  union { float f; unsigned u; } c; c.f = f;
  unsigned r = c.u + 0x7fff + ((c.u >> 16) & 1);
  return (ushort)(r >> 16);
}
__device__ __forceinline__ float bf2f(ushort b){
  union { unsigned u; float f; } c; c.u = ((unsigned)b) << 16; return c.f;
}

// ---------- fused weight prep: WinT, WoutT (32x32 transpose tiles) + WxT ----------
__device__ __forceinline__ void tconv_tile(const float* __restrict__ src, ushort* __restrict__ dst,
    int R, int C, int r0, int c0, float (*tile)[33]){
  int t = threadIdx.x, ci = t & 31, rq = t >> 5;
  #pragma unroll
  for (int p=0;p<4;p++){ int ri = p*8 + rq; tile[ri][ci] = src[(size_t)(r0+ri)*C + c0 + ci]; }
  __syncthreads();
  #pragma unroll
  for (int p=0;p<4;p++){ int ri = p*8 + rq; dst[(size_t)(c0+ri)*R + r0 + ci] = f2bf(tile[ci][ri]); }
}

__global__ __launch_bounds__(256) void k_prep(const float* __restrict__ Win,
    const float* __restrict__ Wout, const float* __restrict__ Wx,
    ushort* __restrict__ WinT, ushort* __restrict__ WoutT, ushort* __restrict__ WxT){
  __shared__ float tile[32][33];
  int bid = blockIdx.x;
  if (bid < 2048){                       // Win [l][256][2048] -> WinT [l][2048][256]
    int x = bid & 63, y = (bid >> 6) & 7, l = bid >> 9;
    tconv_tile(Win + (size_t)l*DM*2*DI, WinT + (size_t)l*2*DI*DM, DM, 2*DI, y*32, x*32, tile);
  } else if (bid < 3072){                // Wout [l][1024][256] -> WoutT [l][256][1024]
    int b = bid - 2048;
    int x = b & 7, y = (b >> 3) & 31, l = b >> 8;
    tconv_tile(Wout + (size_t)l*DI*DM, WoutT + (size_t)l*DM*DI, DI, DM, y*32, x*32, tile);
  } else {                               // Wx [l][1024][80] -> WxT [l][80][1024]
    int b = bid - 3072;
    int x = b & 3, y = (b >> 2) % 80, l = b / 320;
    int k = x*256 + threadIdx.x;
    WxT[(size_t)l*80*DI + (size_t)y*DI + k] = f2bf(Wx[(size_t)l*DI*80 + (size_t)k*80 + y]);
  }
}

// ---------- proj_in + rmsnorm(layer0): 16 rows/block, coalesced Wp ----------
__global__ __launch_bounds__(256) void k_proj_in(const float* __restrict__ x,
    const float* __restrict__ Wp, const float* __restrict__ bp,
    const float* __restrict__ nw, float* __restrict__ h, ushort* __restrict__ xn){
  __shared__ float xs[16][80];
  __shared__ float sred[16][4];
  __shared__ float ssc[16];
  int row0 = blockIdx.x*16;
  int t = threadIdx.x, wid = t>>6;
  if (t < IDIM){
    #pragma unroll
    for (int r=0;r<16;r++) xs[r][t] = x[(size_t)(row0+r)*IDIM + t];
  }
  __syncthreads();
  int col = t;
  float acc[16];
  float b0 = bp[col];
  #pragma unroll
  for (int r=0;r<16;r++) acc[r] = b0;
  for (int k=0;k<IDIM;k++){
    float wv = Wp[k*DM + col];
    #pragma unroll
    for (int r=0;r<16;r++) acc[r] = fmaf(xs[r][k], wv, acc[r]);
  }
  // per-row ssq reduce
  #pragma unroll
  for (int r=0;r<16;r++){
    float sq = acc[r]*acc[r];
    #pragma unroll
    for (int o=32;o>0;o>>=1) sq += __shfl_xor(sq, o);
    if ((t&63)==0) sred[r][wid] = sq;
  }
  __syncthreads();
  if (t < 16){
    float tot = sred[t][0]+sred[t][1]+sred[t][2]+sred[t][3];
    ssc[t] = rsqrtf(tot*(1.0f/DM) + 1e-5f);
  }
  __syncthreads();
  float nwv = nw[col];
  #pragma unroll
  for (int r=0;r<16;r++){
    size_t o = (size_t)(row0+r)*DM + col;
    h[o] = acc[r];
    xn[o] = f2bf(acc[r]*ssc[r]*nwv);
  }
}

// ---------- k_blk0: barrier-free direct-register MFMA GEMM, 128x128, K=256 ----------
// xn @ WinT^T ; conv/silu epilogue -> xi / sz
__global__ __launch_bounds__(256) void k_blk0(
    const ushort* __restrict__ A,     // xn [4096][256]
    const ushort* __restrict__ Bt,    // WinT [2048][256]
    const float* __restrict__ cwl, const float* __restrict__ cbl,
    ushort* __restrict__ xi, ushort* __restrict__ sz)
{
  int t = threadIdx.x;
  int row0 = blockIdx.x*128, col0 = blockIdx.y*128;
  int wid = t>>6, lane = t&63;
  int wr = wid>>1, wc = wid&1, lr = lane&15, lk = lane>>4;
  const ushort* Aw = A  + (size_t)(row0 + wr*64 + lr)*DM + lk*8;
  const ushort* Bw = Bt + (size_t)(col0 + wc*64 + lr)*DM + lk*8;
  f32x4 acc[4][4] = {};
  #pragma unroll
  for (int kc=0; kc<DM/32; ++kc){
    bf16x8 av[4], bv[4];
    #pragma unroll
    for (int i=0;i<4;i++) av[i] = *(const bf16x8*)(Aw + (size_t)i*16*DM + kc*32);
    #pragma unroll
    for (int j=0;j<4;j++) bv[j] = *(const bf16x8*)(Bw + (size_t)j*16*DM + kc*32);
    #pragma unroll
    for (int i=0;i<4;i++)
      #pragma unroll
      for (int j=0;j<4;j++)
        acc[i][j] = __builtin_amdgcn_mfma_f32_16x16x32_bf16(av[i], bv[j], acc[i][j], 0,0,0);
  }
  #pragma unroll
  for (int i=0;i<4;i++)
    #pragma unroll
    for (int j=0;j<4;j++){
      int colb = col0 + wc*64 + j*16 + lr;
      #pragma unroll
      for (int r=0;r<4;r++){
        int rowb = row0 + wr*64 + i*16 + lk*4 + r;
        float v = acc[i][j][r];
        if (colb < DI) xi[(size_t)rowb*DI + colb] = f2bf(siluf(fmaf(cwl[colb*16+15], v, cbl[colb])));
        else           sz[(size_t)rowb*DI + colb - DI] = f2bf(siluf(v));
      }
    }
}

// ---------- k_ssmblk1: fused dbc-MFMA + delta/gating (y->LDS) + y @ WoutT^T + residual + rmsnorm/final ----------
// 16 rows/block, 512 threads (8 waves)
template<int LAST>
__global__ __launch_bounds__(512) void k_ssmblk1(
    const ushort* __restrict__ xi, const ushort* __restrict__ sz,
    const ushort* __restrict__ WxT, const float* __restrict__ Wdt,
    const float* __restrict__ bdt, const float* __restrict__ Dd,
    const ushort* __restrict__ WoutT, float* __restrict__ h,
    const float* __restrict__ nw,    // next-layer norm weight (!LAST)
    const float* __restrict__ Wf, const float* __restrict__ bf,
    ushort* __restrict__ xn, float* __restrict__ out)
{
  __shared__ float dsum[8][16][81];     // 41.5 KB
  __shared__ ushort yl[16][1024];       // 32 KB, XOR-8 chunk swizzled
  __shared__ float sS[16];
  __shared__ float sred[2][8][16];
  __shared__ float ssc[16];
  int r0 = blockIdx.x*16;
  int t = threadIdx.x, w = t>>6, lane = t&63, lr = lane&15, lk = lane>>4;

  // ---- phase 1: dbc[16][80] = xi[16 rows] @ WxT^T, wave w owns k in [w*128,+128)
  {
    f32x4 acc[5] = {};
    const ushort* Ab = xi  + (size_t)(r0+lr)*DI + w*128 + lk*8;
    const ushort* Bb = WxT + (size_t)lr*DI      + w*128 + lk*8;
    #pragma unroll
    for (int s=0;s<4;s++){
      bf16x8 a = *(const bf16x8*)(Ab + s*32);
      #pragma unroll
      for (int j=0;j<5;j++){
        bf16x8 b = *(const bf16x8*)(Bb + (size_t)j*16*DI + s*32);
        acc[j] = __builtin_amdgcn_mfma_f32_16x16x32_bf16(a, b, acc[j], 0,0,0);
      }
    }
    #pragma unroll
    for (int j=0;j<5;j++)
      #pragma unroll
      for (int r=0;r<4;r++)
        dsum[w][lk*4+r][j*16+lr] = acc[j][r];
  }
  __syncthreads();
  for (int idx=t; idx<16*80; idx+=512){
    int rr = idx/80, n = idx%80;
    float s = dsum[0][rr][n];
    #pragma unroll
    for (int q=1;q<8;q++) s += dsum[q][rr][n];
    dsum[0][rr][n] = s;
  }
  __syncthreads();
  if (t < 256){
    int row = t>>4, ln = t&15;
    float p = dsum[0][row][16+ln]*dsum[0][row][48+ln]
            + dsum[0][row][32+ln]*dsum[0][row][64+ln];
    p += __shfl_xor(p, 8); p += __shfl_xor(p, 4); p += __shfl_xor(p, 2); p += __shfl_xor(p, 1);
    if (ln==0) sS[row] = p;
  }
  __syncthreads();

  // ---- phase 2: delta + gating, y into swizzled LDS
  {
    int e = 2*t;
    float2 wdtr[16];
    #pragma unroll
    for (int r=0;r<16;r++) wdtr[r] = *(const float2*)(Wdt + (size_t)r*DI + e);
    float2 bd = *(const float2*)(bdt + e);
    float2 dd = *(const float2*)(Dd + e);
    int c = e>>3, pos = e&7;
    for (int row=0; row<16; ++row){
      float u0 = bd.x, u1 = bd.y;
      #pragma unroll
      for (int r=0;r<16;r++){ float dv = dsum[0][row][r]; u0 = fmaf(wdtr[r].x, dv, u0); u1 = fmaf(wdtr[r].y, dv, u1); }
      float srow = sS[row];
      float d0 = softplusf(u0), d1 = softplusf(u1);
      size_t o = (size_t)(r0+row)*DI + e;
      ushort2 xv = *(const ushort2*)(xi + o);
      ushort2 zv = *(const ushort2*)(sz + o);
      ushort2 ov;
      ov.x = f2bf(bf2f(xv.x) * fmaf(d0, srow, dd.x) * bf2f(zv.x));
      ov.y = f2bf(bf2f(xv.y) * fmaf(d1, srow, dd.y) * bf2f(zv.y));
      *(ushort2*)&yl[row][((c ^ (row&7))<<3) + pos] = ov;
    }
  }
  __syncthreads();

  // ---- phase 3: C[16][256] = y @ WoutT^T, wave w owns cols [w*32,+32); barrier-free B from global
  f32x4 acc3[2] = {};
  {
    const ushort* Bw = WoutT + (size_t)(w*32 + lr)*DI + lk*8;
    #pragma unroll
    for (int kk=0; kk<32; ++kk){
      bf16x8 a = *(const bf16x8*)&yl[lr][(((kk*4+lk) ^ (lr&7))<<3)];
      bf16x8 b0 = *(const bf16x8*)(Bw + kk*32);
      bf16x8 b1 = *(const bf16x8*)(Bw + (size_t)16*DI + kk*32);
      acc3[0] = __builtin_amdgcn_mfma_f32_16x16x32_bf16(a, b0, acc3[0], 0,0,0);
      acc3[1] = __builtin_amdgcn_mfma_f32_16x16x32_bf16(a, b1, acc3[1], 0,0,0);
    }
  }

  // ---- epilogue: residual + per-row reduce (ssq, final dot if LAST)
  float hv[2][4];
  float p[4] = {0,0,0,0}, pf[4] = {0,0,0,0};
  #pragma unroll
  for (int j=0;j<2;j++){
    int colb = w*32 + j*16 + lr;
    #pragma unroll
    for (int r=0;r<4;r++){
      int rowb = lk*4 + r;
      size_t o = (size_t)(r0+rowb)*DM + colb;
      float v = h[o] + acc3[j][r];
      if constexpr (!LAST) h[o] = v;
      hv[j][r] = v;
      p[r] += v*v;
      if constexpr (LAST) pf[r] += v * Wf[colb];
    }
  }
  #pragma unroll
  for (int r=0;r<4;r++){
    #pragma unroll
    for (int o=1;o<16;o<<=1){
      p[r] += __shfl_xor(p[r], o);
      if constexpr (LAST) pf[r] += __shfl_xor(pf[r], o);
    }
  }
  if (lr == 0){
    #pragma unroll
    for (int r=0;r<4;r++){
      sred[0][w][lk*4+r] = p[r];
      if constexpr (LAST) sred[1][w][lk*4+r] = pf[r];
    }
  }
  __syncthreads();
  if (t < 16){
    float tot = 0.f;
    #pragma unroll
    for (int q=0;q<8;q++) tot += sred[0][q][t];
    ssc[t] = rsqrtf(tot*(1.0f/DM) + 1e-5f);
    if constexpr (LAST){
      float ft = 0.f;
      #pragma unroll
      for (int q=0;q<8;q++) ft += sred[1][q][t];
      out[r0 + t] = 1.0f/(1.0f + __expf(-(ft + bf[0])));
    }
  }
  __syncthreads();
  if constexpr (!LAST){
    #pragma unroll
    for (int j=0;j<2;j++){
      int colb = w*32 + j*16 + lr;
      float nwv = nw[colb];
      #pragma unroll
      for (int r=0;r<4;r++){
        int rowb = lk*4 + r;
        xn[(size_t)(r0+rowb)*DM + colb] = f2bf(hv[j][r]*ssc[rowb]*nwv);
      }
    }
  }
}

extern "C" void kernel_launch(void* const* d_in, const int* in_sizes, int n_in,
                              void* d_out, int out_size, void* d_ws, size_t ws_size,
                              hipStream_t stream){
  const float* x   = (const float*)d_in[0];
  const float* Wp  = (const float*)d_in[1];
  const float* bp  = (const float*)d_in[2];
  const float* nw  = (const float*)d_in[3];
  const float* Win = (const float*)d_in[4];
  const float* cw  = (const float*)d_in[5];
  const float* cb  = (const float*)d_in[6];
  const float* Wx  = (const float*)d_in[7];
  const float* Wdt = (const float*)d_in[8];
  const float* bdt = (const float*)d_in[9];
  const float* Dd  = (const float*)d_in[11];   // A_log (d_in[10]) is dead: scan length 1, h0 = 0
  const float* Wout= (const float*)d_in[12];
  const float* Wf  = (const float*)d_in[13];
  const float* bf  = (const float*)d_in[14];
  float* out = (float*)d_out;

  char* wsb = (char*)d_ws;
  float*  h    = (float*)wsb;  wsb += (size_t)BATCH*DM*4;          // 4 MB
  ushort* xn   = (ushort*)wsb; wsb += (size_t)BATCH*DM*2;          // 2 MB
  ushort* xi   = (ushort*)wsb; wsb += (size_t)BATCH*DI*2;          // 8 MB
  ushort* sz   = (ushort*)wsb; wsb += (size_t)BATCH*DI*2;          // 8 MB
  ushort* WinT = (ushort*)wsb; wsb += (size_t)NL*2*DI*DM*2;        // 4 MB
  ushort* WoutT= (ushort*)wsb; wsb += (size_t)NL*DM*DI*2;          // 2 MB
  ushort* WxT  = (ushort*)wsb; wsb += (size_t)NL*80*DI*2;          // 0.64 MB

  k_prep<<<4352, 256, 0, stream>>>(Win, Wout, Wx, WinT, WoutT, WxT);
  k_proj_in<<<BATCH/16, 256, 0, stream>>>(x, Wp, bp, nw, h, xn);
  for (int l=0;l<NL;l++){
    k_blk0<<<dim3(BATCH/128, (2*DI)/128), 256, 0, stream>>>(
        xn, WinT + (size_t)l*2*DI*DM,
        cw + (size_t)l*DI*16, cb + (size_t)l*DI, xi, sz);
    if (l < NL-1)
      k_ssmblk1<0><<<BATCH/16, 512, 0, stream>>>(xi, sz, WxT + (size_t)l*80*DI,
          Wdt + (size_t)l*16*DI, bdt + (size_t)l*DI, Dd + (size_t)l*DI,
          WoutT + (size_t)l*DM*DI, h, nw + (l+1)*DM, nullptr, nullptr, xn, nullptr);
    else
      k_ssmblk1<1><<<BATCH/16, 512, 0, stream>>>(xi, sz, WxT + (size_t)l*80*DI,
          Wdt + (size_t)l*16*DI, bdt + (size_t)l*DI, Dd + (size_t)l*DI,
          WoutT + (size_t)l*DM*DI, h, nullptr, Wf, bf, nullptr, out);
  }
}